// Round 8
// baseline (849.339 us; speedup 1.0000x reference)
//
#include <hip/hip_runtime.h>
#include <hip/hip_bf16.h>
#include <stdint.h>

// TransformerEncoder on MI355X. B=2,S=2048,D=512,H=8,DH=64,F=2048,L=6.
// R8: FFN2 as 128x128xBK64 K-split(x4) with bf16 partials + reduce kernel
//     (halves staged bytes vs 64x64; m97-class MFMA density at 2 blk/CU);
//     attention NCHUNK 4->8 (grid 4096, LDS-capped 6 blk/CU fully fed).

typedef __bf16 bf16x8 __attribute__((ext_vector_type(8)));
typedef __bf16 bf16x4 __attribute__((ext_vector_type(4)));
typedef float f32x4 __attribute__((ext_vector_type(4)));
typedef unsigned short u16;
typedef unsigned short u16x8 __attribute__((ext_vector_type(8)));

#define NB 2
#define NS 2048
#define ND 512
#define NH 8
#define NDH 64
#define NF 2048
#define NL 6
#define NCHUNK 8
#define CK (NS / NCHUNK)  // 256 keys per chunk
#define LOG2E 1.4426950408889634f
#define QSCALE (0.125f * LOG2E)

#if defined(__has_builtin)
#if __has_builtin(__builtin_amdgcn_global_load_lds)
#define HAVE_GLDS 1
#endif
#endif
#ifndef HAVE_GLDS
#define HAVE_GLDS 0
#endif

#if HAVE_GLDS
__device__ __forceinline__ void glds16(const u16* g, u16* l) {
  __builtin_amdgcn_global_load_lds(
      (const __attribute__((address_space(1))) unsigned int*)g,
      (__attribute__((address_space(3))) unsigned int*)l, 16, 0, 0);
}
#endif

__device__ __forceinline__ u16 f2bf(float f) {
  unsigned u = __float_as_uint(f);
  u += 0x7FFFu + ((u >> 16) & 1u);
  return (u16)(u >> 16);
}

// ---------------- weight convert + transpose: f32 [K,N] -> bf16 [N,K] ------
__global__ __launch_bounds__(256) void wcvt_t(const float* __restrict__ src,
                                              u16* __restrict__ dst,
                                              int K, int N) {
  __shared__ float tile[32][33];
  int l = blockIdx.z;
  const float* s = src + (size_t)l * K * N;
  u16* d = dst + (size_t)l * K * N;
  int k0 = blockIdx.y * 32, n0 = blockIdx.x * 32;
  int tx = threadIdx.x, ty = threadIdx.y;  // 32x8
  for (int i = 0; i < 32; i += 8)
    tile[ty + i][tx] = s[(size_t)(k0 + ty + i) * N + n0 + tx];
  __syncthreads();
  for (int i = 0; i < 32; i += 8)
    d[(size_t)(n0 + ty + i) * K + k0 + tx] = f2bf(tile[tx][ty + i]);
}

// ---------------- LayerNorm: fp32 in, bf16 (or f32) out --------------------
template <int OUT_BF16>
__global__ __launch_bounds__(256) void ln_k(const float* __restrict__ x,
                                            const float* __restrict__ w,
                                            const float* __restrict__ b,
                                            void* __restrict__ out) {
  int row = blockIdx.x;
  int t = threadIdx.x;  // 256 threads, D=512 -> one float2 each
  const float* xr = x + (size_t)row * ND;
  float2 v = ((const float2*)xr)[t];
  float s = v.x + v.y, ss = v.x * v.x + v.y * v.y;
  for (int o = 32; o > 0; o >>= 1) {
    s += __shfl_down(s, o);
    ss += __shfl_down(ss, o);
  }
  __shared__ float rs[4], rss[4];
  if ((t & 63) == 0) { rs[t >> 6] = s; rss[t >> 6] = ss; }
  __syncthreads();
  float S = rs[0] + rs[1] + rs[2] + rs[3];
  float SS = rss[0] + rss[1] + rss[2] + rss[3];
  float mean = S * (1.0f / ND);
  float var = SS * (1.0f / ND) - mean * mean;
  float rstd = rsqrtf(var + 1e-5f);
  float2 wv = ((const float2*)w)[t];
  float2 bv = ((const float2*)b)[t];
  float y0 = (v.x - mean) * rstd * wv.x + bv.x;
  float y1 = (v.y - mean) * rstd * wv.y + bv.y;
  if (OUT_BF16) {
    ushort2 p; p.x = f2bf(y0); p.y = f2bf(y1);
    ((ushort2*)out)[(size_t)row * (ND / 2) + t] = p;
  } else {
    float2 p; p.x = y0; p.y = y1;
    ((float2*)out)[(size_t)row * (ND / 2) + t] = p;
  }
}

// ---------------- GEMM: C[M,N] = A[M,K](bf16) @ Bt[N,K]^T(bf16) + bias -----
// EPI: 0 = bf16 out (bias per col), 1 = relu -> bf16, 2 = +resid -> f32,
//      3 = bf16 out, bias per ROW (V-transposed GEMM),
//      4 = bf16 PARTIAL out (no bias; C offset kc*M*N) for K-split.
// KSPLIT: blockIdx.z = k-chunk; A/Bt row stride is full K, loop K/KSPLIT.
// LDS row stride BK u16; slot(row, cb) = cb ^ (row & (BK/8-1)).
template <int EPI, int BM, int BN, int BK, int KSPLIT = 1>
__global__ __launch_bounds__(256) void gemm_bt(const u16* __restrict__ A,
                                               const u16* __restrict__ Bt,
                                               const float* __restrict__ bias,
                                               const float* __restrict__ resid,
                                               void* __restrict__ C,
                                               int M, int N, int K) {
  constexpr int MT = BM / 32;       // m-frags per wave
  constexpr int NT = BN / 32;       // n-frags per wave
  constexpr int CB = BK / 8;        // colblocks (8 or 16)
  constexpr int RPP = 2048 / BK;    // rows staged per pass (32 or 16)
  constexpr int AP = BM / RPP;      // staging passes
  constexpr int BP = BN / RPP;
  constexpr int KK = BK / 32;       // k-subtiles per barrier
  __shared__ u16 la[BM * BK];
  __shared__ u16 lb[BN * BK];
  int bm = blockIdx.y, bn = blockIdx.x;
  int kc = (KSPLIT > 1) ? blockIdx.z : 0;
  int klen = K / KSPLIT;
  int kbase = kc * klen;
  int t = threadIdx.x;
  int wave = t >> 6, lane = t & 63, quad = lane >> 4, l15 = lane & 15;
  int wm = (wave >> 1) * (BM / 2), wn = (wave & 1) * (BN / 2);
  f32x4 acc[MT][NT] = {};
  int srow = t / CB;
  int scol = ((t % CB) ^ (srow & (CB - 1))) * 8;  // swizzled global colblk
  const u16* Ag = A + (size_t)(bm * BM) * K + kbase;
  const u16* Bg = Bt + (size_t)(bn * BN) * K + kbase;
#if HAVE_GLDS
  u16* laB = la + wave * 512;  // lane i -> +16B*i
  u16* lbB = lb + wave * 512;
#endif
  for (int k0 = 0; k0 < klen; k0 += BK) {
    __syncthreads();
#if HAVE_GLDS
#pragma unroll
    for (int g = 0; g < AP; g++)
      glds16(&Ag[(size_t)(srow + g * RPP) * K + k0 + scol], laB + g * 2048);
#pragma unroll
    for (int g = 0; g < BP; g++)
      glds16(&Bg[(size_t)(srow + g * RPP) * K + k0 + scol], lbB + g * 2048);
#else
#pragma unroll
    for (int g = 0; g < AP; g++)
      *(bf16x8*)&la[(srow + g * RPP) * BK + (t % CB) * 8] =
          *(const bf16x8*)&Ag[(size_t)(srow + g * RPP) * K + k0 + scol];
#pragma unroll
    for (int g = 0; g < BP; g++)
      *(bf16x8*)&lb[(srow + g * RPP) * BK + (t % CB) * 8] =
          *(const bf16x8*)&Bg[(size_t)(srow + g * RPP) * K + k0 + scol];
#endif
    __syncthreads();
#pragma unroll
    for (int kk = 0; kk < KK; kk++) {
      bf16x8 af[MT], bfr[NT];
#pragma unroll
      for (int i = 0; i < MT; i++) {
        int row = wm + i * 16 + l15;
        af[i] = *(const bf16x8*)&la[row * BK + ((kk * 4 + quad) ^ (row & (CB - 1))) * 8];
      }
#pragma unroll
      for (int i = 0; i < NT; i++) {
        int row = wn + i * 16 + l15;
        bfr[i] = *(const bf16x8*)&lb[row * BK + ((kk * 4 + quad) ^ (row & (CB - 1))) * 8];
      }
#pragma unroll
      for (int mt = 0; mt < MT; mt++)
#pragma unroll
        for (int nt = 0; nt < NT; nt++)
          acc[mt][nt] = __builtin_amdgcn_mfma_f32_16x16x32_bf16(
              af[mt], bfr[nt], acc[mt][nt], 0, 0, 0);
    }
  }
#pragma unroll
  for (int mt = 0; mt < MT; mt++)
#pragma unroll
    for (int nt = 0; nt < NT; nt++) {
      int col = bn * BN + wn + nt * 16 + l15;
      float bcol = (EPI == 3 || EPI == 4) ? 0.f : bias[col];
#pragma unroll
      for (int r = 0; r < 4; r++) {
        int row = bm * BM + wm + mt * 16 + quad * 4 + r;
        float v = acc[mt][nt][r] + ((EPI == 3) ? bias[row] : bcol);
        if (EPI == 1) v = fmaxf(v, 0.f);
        if (EPI == 2)
          ((float*)C)[(size_t)row * N + col] = v + resid[(size_t)row * N + col];
        else if (EPI == 4)
          ((u16*)C)[(size_t)kc * M * N + (size_t)row * N + col] = f2bf(v);
        else
          ((u16*)C)[(size_t)row * N + col] = f2bf(v);
      }
    }
}

// ---------------- K-split partial reduce: sum 4 bf16 partials + bias + resid
__global__ __launch_bounds__(256) void ksplit_red(const u16* __restrict__ part,
                                                  const float* __restrict__ bias,
                                                  const float* __restrict__ resid,
                                                  float* __restrict__ out) {
  // 4096x512 elems, 8 per thread
  int gt = blockIdx.x * 256 + threadIdx.x;   // [0, 262144)
  int col = (gt & 63) * 8;
  int row = gt >> 6;
  size_t base = (size_t)row * ND + col;
  float acc[8];
#pragma unroll
  for (int j = 0; j < 8; j++) acc[j] = bias[col + j] + resid[base + j];
#pragma unroll
  for (int c = 0; c < 4; c++) {
    bf16x8 v = *(const bf16x8*)&part[(size_t)c * (NB * NS) * ND + base];
#pragma unroll
    for (int j = 0; j < 8; j++) acc[j] += (float)v[j];
  }
#pragma unroll
  for (int j = 0; j < 2; j++)
    *(float4*)&out[base + j * 4] =
        make_float4(acc[j * 4], acc[j * 4 + 1], acc[j * 4 + 2], acc[j * 4 + 3]);
}

// ---------------- Flash attention, split-KV, no-max softmax ----------------
// qk: [B*S, 2*D] bf16 (q|k per token). vt: [D, B*S] bf16 (row=h*64+dh).
// p = exp2(s_scaled + mask*log2e), Q pre-scaled by 0.125*log2e;
// l via ones-B MFMA. kt_s/vt_s XOR-swizzled, P stride 68. 64 q-rows/block.
__global__ __launch_bounds__(256) void attn_k(const u16* __restrict__ qk,
                                              const u16* __restrict__ vt,
                                              const float* __restrict__ mask,
                                              u16* __restrict__ opart,
                                              float* __restrict__ lbuf) {
  __shared__ u16 kt_s[64 * 64];   // K tile, swizzled
  __shared__ u16 vt_s[64 * 64];   // V^T tile, swizzled
  __shared__ u16 p_s[4][16 * 68]; // per-wave P, stride 68
  int bh = blockIdx.y;
  int b = bh >> 3, h = bh & 7;
  int qt = blockIdx.x;
  int c = blockIdx.z;
  int t = threadIdx.x;
  int wave = t >> 6, lane = t & 63, quad = lane >> 4, l15 = lane & 15;

  int qrow = qt * 64 + wave * 16 + l15;
  const u16* qbase = qk + ((size_t)(b * NS + qrow)) * (2 * ND) + h * NDH;
  bf16x8 qf[2];
  qf[0] = *(const bf16x8*)&qbase[quad * 8];
  qf[1] = *(const bf16x8*)&qbase[32 + quad * 8];
#pragma unroll
  for (int e = 0; e < 8; e++) {
    qf[0][e] = (__bf16)((float)qf[0][e] * QSCALE);
    qf[1][e] = (__bf16)((float)qf[1][e] * QSCALE);
  }
  bf16x8 ones;
#pragma unroll
  for (int e = 0; e < 8; e++) ones[e] = (__bf16)1.0f;

  f32x4 oacc[4] = {};
  f32x4 ls = {};  // row-sums of P (all 16 cols identical)

  int srow8 = t >> 3;
  int segsw = ((t & 7) ^ ((t >> 3) & 7)) * 8;  // swizzled fetch colblk
  const u16* kg0 = qk + ((size_t)(b * NS + srow8)) * (2 * ND) + ND + h * NDH + segsw;
  const u16* vg0 = vt + ((size_t)(h * NDH + srow8)) * (NB * NS) + b * NS + segsw;
#if HAVE_GLDS
  u16* ktB = kt_s + wave * 512;
  u16* vtB = vt_s + wave * 512;
#endif
  for (int kt0 = c * CK; kt0 < (c + 1) * CK; kt0 += 64) {
    // mask for this tile's columns (in log2e units)
    float m2[4];
#pragma unroll
    for (int nt = 0; nt < 4; nt++)
      m2[nt] = mask[b * NS + kt0 + nt * 16 + l15] * LOG2E;
    __syncthreads();
#if HAVE_GLDS
    glds16(&kg0[(size_t)kt0 * (2 * ND)], ktB);
    glds16(&kg0[(size_t)(kt0 + 32) * (2 * ND)], ktB + 2048);
    glds16(&vg0[kt0], vtB);
    glds16(&vg0[kt0 + (size_t)32 * (NB * NS)], vtB + 2048);
#else
    *(bf16x8*)&kt_s[srow8 * 64 + (t & 7) * 8] =
        *(const bf16x8*)&kg0[(size_t)kt0 * (2 * ND)];
    *(bf16x8*)&kt_s[(srow8 + 32) * 64 + (t & 7) * 8] =
        *(const bf16x8*)&kg0[(size_t)(kt0 + 32) * (2 * ND)];
    *(bf16x8*)&vt_s[srow8 * 64 + (t & 7) * 8] = *(const bf16x8*)&vg0[kt0];
    *(bf16x8*)&vt_s[(srow8 + 32) * 64 + (t & 7) * 8] =
        *(const bf16x8*)&vg0[kt0 + (size_t)32 * (NB * NS)];
#endif
    __syncthreads();
    // S = Qs @ K^T (swizzled reads)
    f32x4 sc[4] = {};
#pragma unroll
    for (int nt = 0; nt < 4; nt++) {
      int row = nt * 16 + l15;
      bf16x8 kf0 = *(const bf16x8*)&kt_s[row * 64 + (quad ^ (row & 7)) * 8];
      bf16x8 kf1 = *(const bf16x8*)&kt_s[row * 64 + ((quad + 4) ^ (row & 7)) * 8];
      sc[nt] = __builtin_amdgcn_mfma_f32_16x16x32_bf16(qf[0], kf0, sc[nt], 0, 0, 0);
      sc[nt] = __builtin_amdgcn_mfma_f32_16x16x32_bf16(qf[1], kf1, sc[nt], 0, 0, 0);
    }
    // p = exp2(s + m2); pack to bf16; store to per-wave P (stride 68)
    u16* pw = &p_s[wave][0];
#pragma unroll
    for (int nt = 0; nt < 4; nt++) {
#pragma unroll
      for (int rp = 0; rp < 2; rp++) {
        float2 pp;
        pp.x = __builtin_amdgcn_exp2f(sc[nt][2 * rp] + m2[nt]);
        pp.y = __builtin_amdgcn_exp2f(sc[nt][2 * rp + 1] + m2[nt]);
        __hip_bfloat162 bb = __float22bfloat162_rn(pp);
        ushort2 us = *reinterpret_cast<ushort2*>(&bb);
        pw[(quad * 4 + 2 * rp) * 68 + nt * 16 + l15] = us.x;
        pw[(quad * 4 + 2 * rp + 1) * 68 + nt * 16 + l15] = us.y;
      }
    }
    asm volatile("s_waitcnt lgkmcnt(0)" ::: "memory");
    // O += P @ V ; l += P @ ones
#pragma unroll
    for (int kk = 0; kk < 2; kk++) {
      bf16x4 plo = *(const bf16x4*)&pw[l15 * 68 + kk * 32 + quad * 8];
      bf16x4 phi = *(const bf16x4*)&pw[l15 * 68 + kk * 32 + quad * 8 + 4];
      bf16x8 pf = __builtin_shufflevector(plo, phi, 0, 1, 2, 3, 4, 5, 6, 7);
#pragma unroll
      for (int nt = 0; nt < 4; nt++) {
        int row = nt * 16 + l15;
        bf16x8 vf = *(const bf16x8*)&vt_s[row * 64 + ((kk * 4 + quad) ^ (row & 7)) * 8];
        oacc[nt] = __builtin_amdgcn_mfma_f32_16x16x32_bf16(pf, vf, oacc[nt], 0, 0, 0);
      }
      ls = __builtin_amdgcn_mfma_f32_16x16x32_bf16(pf, ones, ls, 0, 0, 0);
    }
  }
  // store un-normalized partial O (bf16) + l per row
  u16* ob = opart + (((size_t)(c * NB * NH + bh) * NS) + qt * 64 + wave * 16) * NDH;
#pragma unroll
  for (int nt = 0; nt < 4; nt++)
#pragma unroll
    for (int r = 0; r < 4; r++)
      ob[(size_t)(quad * 4 + r) * NDH + nt * 16 + l15] = f2bf(oacc[nt][r]);
  if (l15 == 0) {
    size_t li = (size_t)(c * NB * NH + bh) * NS + qt * 64 + wave * 16 + quad * 4;
#pragma unroll
    for (int r = 0; r < 4; r++) lbuf[li + r] = ls[r];
  }
}

// ---------------- merge split-KV partials -> o [B*S, D] bf16 ---------------
__global__ __launch_bounds__(256) void attn_merge(const u16* __restrict__ opart,
                                                  const float* __restrict__ lbuf,
                                                  u16* __restrict__ o) {
  int gt = blockIdx.x * 256 + threadIdx.x;  // [0, 16*2048*8)
  int grp = gt & 7;
  int s = (gt >> 3) & (NS - 1);
  int bh = gt >> 14;
  float L = 0.f;
#pragma unroll
  for (int c = 0; c < NCHUNK; c++)
    L += lbuf[(size_t)(c * NB * NH + bh) * NS + s];
  float inv = 1.0f / L;
  float acc[8] = {};
#pragma unroll
  for (int c = 0; c < NCHUNK; c++) {
    bf16x8 ov = *(const bf16x8*)&opart[((size_t)(c * NB * NH + bh) * NS + s) * NDH + grp * 8];
#pragma unroll
    for (int j = 0; j < 8; j++) acc[j] += (float)ov[j];
  }
  u16x8 res;
#pragma unroll
  for (int j = 0; j < 8; j++) res[j] = f2bf(acc[j] * inv);
  int b = bh >> 3, h = bh & 7;
  *(u16x8*)&o[((size_t)(b * NS + s)) * ND + h * NDH + grp * 8] = res;
}

// ---------------------------------------------------------------------------
extern "C" void kernel_launch(void* const* d_in, const int* in_sizes, int n_in,
                              void* d_out, int out_size, void* d_ws, size_t ws_size,
                              hipStream_t stream) {
  const float* x = (const float*)d_in[0];
  const float* mask = (const float*)d_in[1];
  const float* ln1w = (const float*)d_in[2];
  const float* ln1b = (const float*)d_in[3];
  const float* in_w = (const float*)d_in[4];
  const float* in_b = (const float*)d_in[5];
  const float* out_w = (const float*)d_in[6];
  const float* out_b = (const float*)d_in[7];
  const float* ln2w = (const float*)d_in[8];
  const float* ln2b = (const float*)d_in[9];
  const float* f1w = (const float*)d_in[10];
  const float* f1b = (const float*)d_in[11];
  const float* f2w = (const float*)d_in[12];
  const float* f2b = (const float*)d_in[13];
  const float* normw = (const float*)d_in[14];
  const float* normb = (const float*)d_in[15];

  char* ws = (char*)d_ws;
  auto carve = [&](size_t bytes) {
    char* p = ws;
    ws += (bytes + 255) & ~(size_t)255;
    return p;
  };
  u16* wq_t = (u16*)carve((size_t)NL * 3 * ND * ND * 2);   // [L][3D][D]
  u16* wo_t = (u16*)carve((size_t)NL * ND * ND * 2);       // [L][D][D]
  u16* w1_t = (u16*)carve((size_t)NL * NF * ND * 2);       // [L][F][D]
  u16* w2_t = (u16*)carve((size_t)NL * ND * NF * 2);       // [L][D][F]
  u16* ybuf = (u16*)carve((size_t)NB * NS * ND * 2);
  u16* qk = (u16*)carve((size_t)NB * NS * 2 * ND * 2);     // [M][2D]
  u16* vtb = (u16*)carve((size_t)ND * NB * NS * 2);        // [D][M]
  u16* obuf = (u16*)carve((size_t)NB * NS * ND * 2);
  u16* ubuf = (u16*)carve((size_t)NB * NS * NF * 2);       // FFN mid
  float* hA = (float*)carve((size_t)NB * NS * ND * 4);
  float* hB = (float*)carve((size_t)NB * NS * ND * 4);
  float* lbuf = (float*)carve((size_t)NCHUNK * NB * NH * NS * 4);
  u16* opart = (u16*)carve((size_t)NCHUNK * NB * NH * NS * NDH * 2);  // 33.6MB
  u16* pbuf = (u16*)carve((size_t)4 * NB * NS * ND * 2);   // FFN2 K-split partials

  const int M = NB * NS;  // 4096
  dim3 tb(32, 8);
  wcvt_t<<<dim3(3 * ND / 32, ND / 32, NL), tb, 0, stream>>>(in_w, wq_t, ND, 3 * ND);
  wcvt_t<<<dim3(ND / 32, ND / 32, NL), tb, 0, stream>>>(out_w, wo_t, ND, ND);
  wcvt_t<<<dim3(NF / 32, ND / 32, NL), tb, 0, stream>>>(f1w, w1_t, ND, NF);
  wcvt_t<<<dim3(ND / 32, NF / 32, NL), tb, 0, stream>>>(f2w, w2_t, NF, ND);

  const float* hin = x;
  for (int l = 0; l < NL; l++) {
    ln_k<1><<<M, 256, 0, stream>>>(hin, ln1w + l * ND, ln1b + l * ND, ybuf);
    // Q|K projection: [4096,1024] -- 64x128xBK128, grid 512
    gemm_bt<0, 64, 128, 128><<<dim3(2 * ND / 128, M / 64), 256, 0, stream>>>(
        ybuf, wq_t + (size_t)l * 3 * ND * ND, in_b + l * 3 * ND, nullptr, qk,
        M, 2 * ND, ND);
    // V projection, transposed output: [512,4096] -- 64x64xBK128, grid 512
    gemm_bt<3, 64, 64, 128><<<dim3(M / 64, ND / 64), 256, 0, stream>>>(
        wq_t + (size_t)l * 3 * ND * ND + (size_t)2 * ND * ND, ybuf,
        in_b + l * 3 * ND + 2 * ND, nullptr, vtb, ND, M, ND);
    attn_k<<<dim3(NS / 64, NB * NH, NCHUNK), 256, 0, stream>>>(
        qk, vtb, mask, opart, lbuf);
    attn_merge<<<(NB * NH * NS * 8) / 256, 256, 0, stream>>>(opart, lbuf, obuf);
    // O projection: [4096,512] -- 64x64xBK128, grid 512
    gemm_bt<2, 64, 64, 128><<<dim3(ND / 64, M / 64), 256, 0, stream>>>(
        obuf, wo_t + (size_t)l * ND * ND, out_b + l * ND, hin, hB, M, ND, ND);
    ln_k<1><<<M, 256, 0, stream>>>(hB, ln2w + l * ND, ln2b + l * ND, ybuf);
    // FFN1: [4096,2048] -- 128x128xBK64, grid 512
    gemm_bt<1, 128, 128, 64><<<dim3(NF / 128, M / 128), 256, 0, stream>>>(
        ybuf, w1_t + (size_t)l * NF * ND, f1b + l * NF, nullptr, ubuf, M, NF, ND);
    // FFN2: [4096,512]x K-split(4) -- 128x128xBK64 partials, grid 4x32x4=512
    gemm_bt<4, 128, 128, 64, 4><<<dim3(ND / 128, M / 128, 4), 256, 0, stream>>>(
        ubuf, w2_t + (size_t)l * ND * NF, nullptr, nullptr, pbuf, M, ND, NF);
    ksplit_red<<<(M * ND / 8) / 256, 256, 0, stream>>>(
        pbuf, f2b + l * ND, hB, hA);
    hin = hA;
  }
  ln_k<0><<<M, 256, 0, stream>>>(hA, normw, normb, (float*)d_out);
}

// Round 9
// 838.108 us; speedup vs baseline: 1.0134x; 1.0134x over previous
//
#include <hip/hip_runtime.h>
#include <hip/hip_bf16.h>
#include <stdint.h>

// TransformerEncoder on MI355X. B=2,S=2048,D=512,H=8,DH=64,F=2048,L=6.
// R9: NCHUNK back to 4 (measured 40.6us attn). Oproj+FFN2 both 128x128xBK64
//     K-split(x4). Fused red_ln kernel (K-split reduce + bias + resid + LN,
//     one wave per row). QK-proj and Vt-proj fused into one dispatch.

typedef __bf16 bf16x8 __attribute__((ext_vector_type(8)));
typedef __bf16 bf16x4 __attribute__((ext_vector_type(4)));
typedef float f32x4 __attribute__((ext_vector_type(4)));
typedef unsigned short u16;
typedef unsigned short u16x8 __attribute__((ext_vector_type(8)));

#define NB 2
#define NS 2048
#define ND 512
#define NH 8
#define NDH 64
#define NF 2048
#define NL 6
#define NCHUNK 4
#define CK (NS / NCHUNK)  // 512 keys per chunk
#define LOG2E 1.4426950408889634f
#define QSCALE (0.125f * LOG2E)

#if defined(__has_builtin)
#if __has_builtin(__builtin_amdgcn_global_load_lds)
#define HAVE_GLDS 1
#endif
#endif
#ifndef HAVE_GLDS
#define HAVE_GLDS 0
#endif

#if HAVE_GLDS
__device__ __forceinline__ void glds16(const u16* g, u16* l) {
  __builtin_amdgcn_global_load_lds(
      (const __attribute__((address_space(1))) unsigned int*)g,
      (__attribute__((address_space(3))) unsigned int*)l, 16, 0, 0);
}
#endif

__device__ __forceinline__ u16 f2bf(float f) {
  unsigned u = __float_as_uint(f);
  u += 0x7FFFu + ((u >> 16) & 1u);
  return (u16)(u >> 16);
}

// ---------------- weight convert + transpose: f32 [K,N] -> bf16 [N,K] ------
__global__ __launch_bounds__(256) void wcvt_t(const float* __restrict__ src,
                                              u16* __restrict__ dst,
                                              int K, int N) {
  __shared__ float tile[32][33];
  int l = blockIdx.z;
  const float* s = src + (size_t)l * K * N;
  u16* d = dst + (size_t)l * K * N;
  int k0 = blockIdx.y * 32, n0 = blockIdx.x * 32;
  int tx = threadIdx.x, ty = threadIdx.y;  // 32x8
  for (int i = 0; i < 32; i += 8)
    tile[ty + i][tx] = s[(size_t)(k0 + ty + i) * N + n0 + tx];
  __syncthreads();
  for (int i = 0; i < 32; i += 8)
    d[(size_t)(n0 + ty + i) * K + k0 + tx] = f2bf(tile[tx][ty + i]);
}

// ---------------- LayerNorm (standalone, layer-0 ln1 only) -----------------
__global__ __launch_bounds__(256) void ln_k(const float* __restrict__ x,
                                            const float* __restrict__ w,
                                            const float* __restrict__ b,
                                            u16* __restrict__ out) {
  int row = blockIdx.x;
  int t = threadIdx.x;
  const float* xr = x + (size_t)row * ND;
  float2 v = ((const float2*)xr)[t];
  float s = v.x + v.y, ss = v.x * v.x + v.y * v.y;
  for (int o = 32; o > 0; o >>= 1) {
    s += __shfl_down(s, o);
    ss += __shfl_down(ss, o);
  }
  __shared__ float rs[4], rss[4];
  if ((t & 63) == 0) { rs[t >> 6] = s; rss[t >> 6] = ss; }
  __syncthreads();
  float S = rs[0] + rs[1] + rs[2] + rs[3];
  float SS = rss[0] + rss[1] + rss[2] + rss[3];
  float mean = S * (1.0f / ND);
  float var = SS * (1.0f / ND) - mean * mean;
  float rstd = rsqrtf(var + 1e-5f);
  float2 wv = ((const float2*)w)[t];
  float2 bv = ((const float2*)b)[t];
  ushort2 p;
  p.x = f2bf((v.x - mean) * rstd * wv.x + bv.x);
  p.y = f2bf((v.y - mean) * rstd * wv.y + bv.y);
  ((ushort2*)out)[(size_t)row * (ND / 2) + t] = p;
}

// ---------------- GEMM device core -----------------------------------------
// C[M,N] = A[M,K](bf16) @ Bt[N,K]^T(bf16) + bias. EPI: 0 bf16+biascol,
// 1 relu bf16, 2 +resid f32, 3 bf16+biasROW, 4 bf16 PARTIAL (kc*M*N offset).
// LDS row stride BK u16; slot(row,cb) = cb ^ (row & (BK/8-1)).
template <int EPI, int BM, int BN, int BK, int KSPLIT>
__device__ __forceinline__ void gemm_dev(u16* la, u16* lb,
                                         const u16* __restrict__ A,
                                         const u16* __restrict__ Bt,
                                         const float* __restrict__ bias,
                                         const float* __restrict__ resid,
                                         void* __restrict__ C,
                                         int M, int N, int K,
                                         int bm, int bn, int kc, int t) {
  constexpr int MT = BM / 32;
  constexpr int NT = BN / 32;
  constexpr int CB = BK / 8;
  constexpr int RPP = 2048 / BK;
  constexpr int AP = BM / RPP;
  constexpr int BP = BN / RPP;
  constexpr int KK = BK / 32;
  int klen = K / KSPLIT;
  int kbase = kc * klen;
  int wave = t >> 6, lane = t & 63, quad = lane >> 4, l15 = lane & 15;
  int wm = (wave >> 1) * (BM / 2), wn = (wave & 1) * (BN / 2);
  f32x4 acc[MT][NT] = {};
  int srow = t / CB;
  int scol = ((t % CB) ^ (srow & (CB - 1))) * 8;
  const u16* Ag = A + (size_t)(bm * BM) * K + kbase;
  const u16* Bg = Bt + (size_t)(bn * BN) * K + kbase;
#if HAVE_GLDS
  u16* laB = la + wave * 512;
  u16* lbB = lb + wave * 512;
#endif
  for (int k0 = 0; k0 < klen; k0 += BK) {
    __syncthreads();
#if HAVE_GLDS
#pragma unroll
    for (int g = 0; g < AP; g++)
      glds16(&Ag[(size_t)(srow + g * RPP) * K + k0 + scol], laB + g * 2048);
#pragma unroll
    for (int g = 0; g < BP; g++)
      glds16(&Bg[(size_t)(srow + g * RPP) * K + k0 + scol], lbB + g * 2048);
#else
#pragma unroll
    for (int g = 0; g < AP; g++)
      *(bf16x8*)&la[(srow + g * RPP) * BK + (t % CB) * 8] =
          *(const bf16x8*)&Ag[(size_t)(srow + g * RPP) * K + k0 + scol];
#pragma unroll
    for (int g = 0; g < BP; g++)
      *(bf16x8*)&lb[(srow + g * RPP) * BK + (t % CB) * 8] =
          *(const bf16x8*)&Bg[(size_t)(srow + g * RPP) * K + k0 + scol];
#endif
    __syncthreads();
#pragma unroll
    for (int kk = 0; kk < KK; kk++) {
      bf16x8 af[MT], bfr[NT];
#pragma unroll
      for (int i = 0; i < MT; i++) {
        int row = wm + i * 16 + l15;
        af[i] = *(const bf16x8*)&la[row * BK + ((kk * 4 + quad) ^ (row & (CB - 1))) * 8];
      }
#pragma unroll
      for (int i = 0; i < NT; i++) {
        int row = wn + i * 16 + l15;
        bfr[i] = *(const bf16x8*)&lb[row * BK + ((kk * 4 + quad) ^ (row & (CB - 1))) * 8];
      }
#pragma unroll
      for (int mt = 0; mt < MT; mt++)
#pragma unroll
        for (int nt = 0; nt < NT; nt++)
          acc[mt][nt] = __builtin_amdgcn_mfma_f32_16x16x32_bf16(
              af[mt], bfr[nt], acc[mt][nt], 0, 0, 0);
    }
  }
#pragma unroll
  for (int mt = 0; mt < MT; mt++)
#pragma unroll
    for (int nt = 0; nt < NT; nt++) {
      int col = bn * BN + wn + nt * 16 + l15;
      float bcol = (EPI == 3 || EPI == 4) ? 0.f : bias[col];
#pragma unroll
      for (int r = 0; r < 4; r++) {
        int row = bm * BM + wm + mt * 16 + quad * 4 + r;
        float v = acc[mt][nt][r] + ((EPI == 3) ? bias[row] : bcol);
        if (EPI == 1) v = fmaxf(v, 0.f);
        if (EPI == 2)
          ((float*)C)[(size_t)row * N + col] = v + resid[(size_t)row * N + col];
        else if (EPI == 4)
          ((u16*)C)[(size_t)kc * M * N + (size_t)row * N + col] = f2bf(v);
        else
          ((u16*)C)[(size_t)row * N + col] = f2bf(v);
      }
    }
}

template <int EPI, int BM, int BN, int BK, int KSPLIT = 1>
__global__ __launch_bounds__(256) void gemm_bt(const u16* __restrict__ A,
                                               const u16* __restrict__ Bt,
                                               const float* __restrict__ bias,
                                               const float* __restrict__ resid,
                                               void* __restrict__ C,
                                               int M, int N, int K) {
  __shared__ u16 la[BM * BK];
  __shared__ u16 lb[BN * BK];
  gemm_dev<EPI, BM, BN, BK, KSPLIT>(la, lb, A, Bt, bias, resid, C, M, N, K,
                                    blockIdx.y, blockIdx.x,
                                    (KSPLIT > 1) ? blockIdx.z : 0, threadIdx.x);
}

// ---------------- fused QK-proj + Vt-proj (independent, one dispatch) ------
// blocks [0,512): QK 64x128xBK128 tiles of [M,1024]; [512,1024): Vt
// 64x64xBK128 tiles of [512,M] (B=ybuf, bias per row).
__global__ __launch_bounds__(256) void qkv_fused(const u16* __restrict__ y,
                                                 const u16* __restrict__ wqk,
                                                 const u16* __restrict__ wv,
                                                 const float* __restrict__ inb,
                                                 u16* __restrict__ qkout,
                                                 u16* __restrict__ vtout) {
  __shared__ u16 smem[(64 + 128) * 128];  // 48KB
  int id = blockIdx.x, t = threadIdx.x;
  const int M = NB * NS;
  if (id < 512) {
    gemm_dev<0, 64, 128, 128, 1>(smem, smem + 64 * 128, y, wqk, inb, nullptr,
                                 qkout, M, 2 * ND, ND, id >> 3, id & 7, 0, t);
  } else {
    id -= 512;
    gemm_dev<3, 64, 64, 128, 1>(smem, smem + 64 * 128, wv, y, inb + 2 * ND,
                                nullptr, vtout, ND, M, ND, id >> 6, id & 63, 0, t);
  }
}

// ---------------- fused K-split reduce + bias + resid + LayerNorm ----------
// One wave per row (64 lanes x 8 cols = 512). Writes h (f32) and LN'd y.
template <int OUT_BF16>
__global__ __launch_bounds__(256) void red_ln(const u16* __restrict__ part,
                                              const float* __restrict__ bias,
                                              const float* __restrict__ resid,
                                              const float* __restrict__ lw,
                                              const float* __restrict__ lbb,
                                              float* __restrict__ hout,
                                              void* __restrict__ yout) {
  int t = threadIdx.x;
  int row = blockIdx.x * 4 + (t >> 6);
  int lane = t & 63;
  int col = lane * 8;
  size_t base = (size_t)row * ND + col;
  float acc[8];
#pragma unroll
  for (int j = 0; j < 8; j++) acc[j] = bias[col + j] + resid[base + j];
#pragma unroll
  for (int c = 0; c < 4; c++) {
    bf16x8 v = *(const bf16x8*)&part[(size_t)c * (NB * NS) * ND + base];
#pragma unroll
    for (int j = 0; j < 8; j++) acc[j] += (float)v[j];
  }
  *(float4*)&hout[base] = make_float4(acc[0], acc[1], acc[2], acc[3]);
  *(float4*)&hout[base + 4] = make_float4(acc[4], acc[5], acc[6], acc[7]);
  float s = 0.f, ss = 0.f;
#pragma unroll
  for (int j = 0; j < 8; j++) { s += acc[j]; ss += acc[j] * acc[j]; }
  for (int o = 1; o < 64; o <<= 1) {
    s += __shfl_xor(s, o);
    ss += __shfl_xor(ss, o);
  }
  float mean = s * (1.0f / ND);
  float var = ss * (1.0f / ND) - mean * mean;
  float rstd = rsqrtf(var + 1e-5f);
  float4 w0 = *(const float4*)&lw[col], w1 = *(const float4*)&lw[col + 4];
  float4 b0 = *(const float4*)&lbb[col], b1 = *(const float4*)&lbb[col + 4];
  float wv[8] = {w0.x, w0.y, w0.z, w0.w, w1.x, w1.y, w1.z, w1.w};
  float bv[8] = {b0.x, b0.y, b0.z, b0.w, b1.x, b1.y, b1.z, b1.w};
  float yv[8];
#pragma unroll
  for (int j = 0; j < 8; j++) yv[j] = (acc[j] - mean) * rstd * wv[j] + bv[j];
  if (OUT_BF16) {
    u16x8 res;
#pragma unroll
    for (int j = 0; j < 8; j++) res[j] = f2bf(yv[j]);
    *(u16x8*)&((u16*)yout)[base] = res;
  } else {
    *(float4*)&((float*)yout)[base] = make_float4(yv[0], yv[1], yv[2], yv[3]);
    *(float4*)&((float*)yout)[base + 4] = make_float4(yv[4], yv[5], yv[6], yv[7]);
  }
}

// ---------------- Flash attention, split-KV, no-max softmax (R5 config) ----
__global__ __launch_bounds__(256) void attn_k(const u16* __restrict__ qk,
                                              const u16* __restrict__ vt,
                                              const float* __restrict__ mask,
                                              u16* __restrict__ opart,
                                              float* __restrict__ lbuf) {
  __shared__ u16 kt_s[64 * 64];   // K tile, swizzled
  __shared__ u16 vt_s[64 * 64];   // V^T tile, swizzled
  __shared__ u16 p_s[4][16 * 68]; // per-wave P, stride 68
  int bh = blockIdx.y;
  int b = bh >> 3, h = bh & 7;
  int qt = blockIdx.x;
  int c = blockIdx.z;
  int t = threadIdx.x;
  int wave = t >> 6, lane = t & 63, quad = lane >> 4, l15 = lane & 15;

  int qrow = qt * 64 + wave * 16 + l15;
  const u16* qbase = qk + ((size_t)(b * NS + qrow)) * (2 * ND) + h * NDH;
  bf16x8 qf[2];
  qf[0] = *(const bf16x8*)&qbase[quad * 8];
  qf[1] = *(const bf16x8*)&qbase[32 + quad * 8];
#pragma unroll
  for (int e = 0; e < 8; e++) {
    qf[0][e] = (__bf16)((float)qf[0][e] * QSCALE);
    qf[1][e] = (__bf16)((float)qf[1][e] * QSCALE);
  }
  bf16x8 ones;
#pragma unroll
  for (int e = 0; e < 8; e++) ones[e] = (__bf16)1.0f;

  f32x4 oacc[4] = {};
  f32x4 ls = {};

  int srow8 = t >> 3;
  int segsw = ((t & 7) ^ ((t >> 3) & 7)) * 8;
  const u16* kg0 = qk + ((size_t)(b * NS + srow8)) * (2 * ND) + ND + h * NDH + segsw;
  const u16* vg0 = vt + ((size_t)(h * NDH + srow8)) * (NB * NS) + b * NS + segsw;
#if HAVE_GLDS
  u16* ktB = kt_s + wave * 512;
  u16* vtB = vt_s + wave * 512;
#endif
  for (int kt0 = c * CK; kt0 < (c + 1) * CK; kt0 += 64) {
    float m2[4];
#pragma unroll
    for (int nt = 0; nt < 4; nt++)
      m2[nt] = mask[b * NS + kt0 + nt * 16 + l15] * LOG2E;
    __syncthreads();
#if HAVE_GLDS
    glds16(&kg0[(size_t)kt0 * (2 * ND)], ktB);
    glds16(&kg0[(size_t)(kt0 + 32) * (2 * ND)], ktB + 2048);
    glds16(&vg0[kt0], vtB);
    glds16(&vg0[kt0 + (size_t)32 * (NB * NS)], vtB + 2048);
#else
    *(bf16x8*)&kt_s[srow8 * 64 + (t & 7) * 8] =
        *(const bf16x8*)&kg0[(size_t)kt0 * (2 * ND)];
    *(bf16x8*)&kt_s[(srow8 + 32) * 64 + (t & 7) * 8] =
        *(const bf16x8*)&kg0[(size_t)(kt0 + 32) * (2 * ND)];
    *(bf16x8*)&vt_s[srow8 * 64 + (t & 7) * 8] = *(const bf16x8*)&vg0[kt0];
    *(bf16x8*)&vt_s[(srow8 + 32) * 64 + (t & 7) * 8] =
        *(const bf16x8*)&vg0[kt0 + (size_t)32 * (NB * NS)];
#endif
    __syncthreads();
    f32x4 sc[4] = {};
#pragma unroll
    for (int nt = 0; nt < 4; nt++) {
      int row = nt * 16 + l15;
      bf16x8 kf0 = *(const bf16x8*)&kt_s[row * 64 + (quad ^ (row & 7)) * 8];
      bf16x8 kf1 = *(const bf16x8*)&kt_s[row * 64 + ((quad + 4) ^ (row & 7)) * 8];
      sc[nt] = __builtin_amdgcn_mfma_f32_16x16x32_bf16(qf[0], kf0, sc[nt], 0, 0, 0);
      sc[nt] = __builtin_amdgcn_mfma_f32_16x16x32_bf16(qf[1], kf1, sc[nt], 0, 0, 0);
    }
    u16* pw = &p_s[wave][0];
#pragma unroll
    for (int nt = 0; nt < 4; nt++) {
#pragma unroll
      for (int rp = 0; rp < 2; rp++) {
        float2 pp;
        pp.x = __builtin_amdgcn_exp2f(sc[nt][2 * rp] + m2[nt]);
        pp.y = __builtin_amdgcn_exp2f(sc[nt][2 * rp + 1] + m2[nt]);
        __hip_bfloat162 bb = __float22bfloat162_rn(pp);
        ushort2 us = *reinterpret_cast<ushort2*>(&bb);
        pw[(quad * 4 + 2 * rp) * 68 + nt * 16 + l15] = us.x;
        pw[(quad * 4 + 2 * rp + 1) * 68 + nt * 16 + l15] = us.y;
      }
    }
    asm volatile("s_waitcnt lgkmcnt(0)" ::: "memory");
#pragma unroll
    for (int kk = 0; kk < 2; kk++) {
      bf16x4 plo = *(const bf16x4*)&pw[l15 * 68 + kk * 32 + quad * 8];
      bf16x4 phi = *(const bf16x4*)&pw[l15 * 68 + kk * 32 + quad * 8 + 4];
      bf16x8 pf = __builtin_shufflevector(plo, phi, 0, 1, 2, 3, 4, 5, 6, 7);
#pragma unroll
      for (int nt = 0; nt < 4; nt++) {
        int row = nt * 16 + l15;
        bf16x8 vf = *(const bf16x8*)&vt_s[row * 64 + ((kk * 4 + quad) ^ (row & 7)) * 8];
        oacc[nt] = __builtin_amdgcn_mfma_f32_16x16x32_bf16(pf, vf, oacc[nt], 0, 0, 0);
      }
      ls = __builtin_amdgcn_mfma_f32_16x16x32_bf16(pf, ones, ls, 0, 0, 0);
    }
  }
  u16* ob = opart + (((size_t)(c * NB * NH + bh) * NS) + qt * 64 + wave * 16) * NDH;
#pragma unroll
  for (int nt = 0; nt < 4; nt++)
#pragma unroll
    for (int r = 0; r < 4; r++)
      ob[(size_t)(quad * 4 + r) * NDH + nt * 16 + l15] = f2bf(oacc[nt][r]);
  if (l15 == 0) {
    size_t li = (size_t)(c * NB * NH + bh) * NS + qt * 64 + wave * 16 + quad * 4;
#pragma unroll
    for (int r = 0; r < 4; r++) lbuf[li + r] = ls[r];
  }
}

// ---------------- merge split-KV partials -> o [B*S, D] bf16 ---------------
__global__ __launch_bounds__(256) void attn_merge(const u16* __restrict__ opart,
                                                  const float* __restrict__ lbuf,
                                                  u16* __restrict__ o) {
  int gt = blockIdx.x * 256 + threadIdx.x;
  int grp = gt & 7;
  int s = (gt >> 3) & (NS - 1);
  int bh = gt >> 14;
  float L = 0.f;
#pragma unroll
  for (int c = 0; c < NCHUNK; c++)
    L += lbuf[(size_t)(c * NB * NH + bh) * NS + s];
  float inv = 1.0f / L;
  float acc[8] = {};
#pragma unroll
  for (int c = 0; c < NCHUNK; c++) {
    bf16x8 ov = *(const bf16x8*)&opart[((size_t)(c * NB * NH + bh) * NS + s) * NDH + grp * 8];
#pragma unroll
    for (int j = 0; j < 8; j++) acc[j] += (float)ov[j];
  }
  u16x8 res;
#pragma unroll
  for (int j = 0; j < 8; j++) res[j] = f2bf(acc[j] * inv);
  int b = bh >> 3, h = bh & 7;
  *(u16x8*)&o[((size_t)(b * NS + s)) * ND + h * NDH + grp * 8] = res;
}

// ---------------------------------------------------------------------------
extern "C" void kernel_launch(void* const* d_in, const int* in_sizes, int n_in,
                              void* d_out, int out_size, void* d_ws, size_t ws_size,
                              hipStream_t stream) {
  const float* x = (const float*)d_in[0];
  const float* mask = (const float*)d_in[1];
  const float* ln1w = (const float*)d_in[2];
  const float* ln1b = (const float*)d_in[3];
  const float* in_w = (const float*)d_in[4];
  const float* in_b = (const float*)d_in[5];
  const float* out_w = (const float*)d_in[6];
  const float* out_b = (const float*)d_in[7];
  const float* ln2w = (const float*)d_in[8];
  const float* ln2b = (const float*)d_in[9];
  const float* f1w = (const float*)d_in[10];
  const float* f1b = (const float*)d_in[11];
  const float* f2w = (const float*)d_in[12];
  const float* f2b = (const float*)d_in[13];
  const float* normw = (const float*)d_in[14];
  const float* normb = (const float*)d_in[15];

  char* ws = (char*)d_ws;
  auto carve = [&](size_t bytes) {
    char* p = ws;
    ws += (bytes + 255) & ~(size_t)255;
    return p;
  };
  u16* wq_t = (u16*)carve((size_t)NL * 3 * ND * ND * 2);   // [L][3D][D]
  u16* wo_t = (u16*)carve((size_t)NL * ND * ND * 2);       // [L][D][D]
  u16* w1_t = (u16*)carve((size_t)NL * NF * ND * 2);       // [L][F][D]
  u16* w2_t = (u16*)carve((size_t)NL * ND * NF * 2);       // [L][D][F]
  u16* ybuf = (u16*)carve((size_t)NB * NS * ND * 2);
  u16* qk = (u16*)carve((size_t)NB * NS * 2 * ND * 2);     // [M][2D]
  u16* vtb = (u16*)carve((size_t)ND * NB * NS * 2);        // [D][M]
  u16* obuf = (u16*)carve((size_t)NB * NS * ND * 2);
  u16* ubuf = (u16*)carve((size_t)NB * NS * NF * 2);       // FFN mid
  float* hA = (float*)carve((size_t)NB * NS * ND * 4);
  float* hB = (float*)carve((size_t)NB * NS * ND * 4);
  float* lbuf = (float*)carve((size_t)NCHUNK * NB * NH * NS * 4);
  u16* opart = (u16*)carve((size_t)NCHUNK * NB * NH * NS * NDH * 2);
  u16* pbuf = (u16*)carve((size_t)4 * NB * NS * ND * 2);   // K-split partials

  const int M = NB * NS;  // 4096
  dim3 tb(32, 8);
  wcvt_t<<<dim3(3 * ND / 32, ND / 32, NL), tb, 0, stream>>>(in_w, wq_t, ND, 3 * ND);
  wcvt_t<<<dim3(ND / 32, ND / 32, NL), tb, 0, stream>>>(out_w, wo_t, ND, ND);
  wcvt_t<<<dim3(NF / 32, ND / 32, NL), tb, 0, stream>>>(f1w, w1_t, ND, NF);
  wcvt_t<<<dim3(ND / 32, NF / 32, NL), tb, 0, stream>>>(f2w, w2_t, NF, ND);

  // layer-0 LN1 (later layers get LN fused into red_ln)
  ln_k<<<M, 256, 0, stream>>>(x, ln1w, ln1b, ybuf);

  const float* hin = x;
  for (int l = 0; l < NL; l++) {
    // fused Q|K proj (blocks 0..511) + Vt proj (blocks 512..1023)
    qkv_fused<<<1024, 256, 0, stream>>>(
        ybuf, wq_t + (size_t)l * 3 * ND * ND,
        wq_t + (size_t)l * 3 * ND * ND + (size_t)2 * ND * ND,
        in_b + l * 3 * ND, qk, vtb);
    attn_k<<<dim3(NS / 64, NB * NH, NCHUNK), 256, 0, stream>>>(
        qk, vtb, mask, opart, lbuf);
    attn_merge<<<(NB * NH * NS * 8) / 256, 256, 0, stream>>>(opart, lbuf, obuf);
    // O projection: 128x128xBK64 K-split(4) partials, grid (4,32,4)=512
    gemm_bt<4, 128, 128, 64, 4><<<dim3(ND / 128, M / 128, 4), 256, 0, stream>>>(
        obuf, wo_t + (size_t)l * ND * ND, nullptr, nullptr, pbuf, M, ND, ND);
    // reduce + out_b + resid(hin) -> hB ; LN2 -> ybuf
    red_ln<1><<<M / 4, 256, 0, stream>>>(pbuf, out_b + l * ND, hin,
                                         ln2w + l * ND, ln2b + l * ND, hB, ybuf);
    // FFN1: 128x128xBK64, grid 512
    gemm_bt<1, 128, 128, 64><<<dim3(NF / 128, M / 128), 256, 0, stream>>>(
        ybuf, w1_t + (size_t)l * NF * ND, f1b + l * NF, nullptr, ubuf, M, NF, ND);
    // FFN2: 128x128xBK64 K-split(4) partials
    gemm_bt<4, 128, 128, 64, 4><<<dim3(ND / 128, M / 128, 4), 256, 0, stream>>>(
        ubuf, w2_t + (size_t)l * ND * NF, nullptr, nullptr, pbuf, M, ND, NF);
    // reduce + f2b + resid(hB) -> hA ; LN1(l+1) or final norm
    if (l < NL - 1)
      red_ln<1><<<M / 4, 256, 0, stream>>>(pbuf, f2b + l * ND, hB,
                                           ln1w + (l + 1) * ND,
                                           ln1b + (l + 1) * ND, hA, ybuf);
    else
      red_ln<0><<<M / 4, 256, 0, stream>>>(pbuf, f2b + l * ND, hB,
                                           normw, normb, hA, (float*)d_out);
    hin = hA;
  }
}